// Round 1
// baseline (380.376 us; speedup 1.0000x reference)
//
#include <hip/hip_runtime.h>
#include <stdint.h>

// Problem constants: B=2, T=512, P=8, D=1024, NH=16, NKV=4, HD=64
// Rows (b,p,t): 16*512 = 8192.

typedef __attribute__((ext_vector_type(8))) short bf16x8;
typedef __attribute__((ext_vector_type(4))) float f32x4;
typedef __attribute__((ext_vector_type(4))) unsigned short us4;

static __device__ __forceinline__ unsigned short f2bf(float f) {
  unsigned u = __float_as_uint(f);
  u += 0x7fffu + ((u >> 16) & 1u);   // RNE
  return (unsigned short)(u >> 16);
}
static __device__ __forceinline__ float bf2f(unsigned short s) {
  return __uint_as_float(((unsigned)s) << 16);
}

static __device__ __forceinline__ void ld_lds16(const void* g, void* l) {
  __builtin_amdgcn_global_load_lds(
      (const __attribute__((address_space(1))) void*)g,
      (__attribute__((address_space(3))) void*)l, 16, 0, 0);
}

static __device__ __forceinline__ f32x4 mfma16(bf16x8 a, bf16x8 b, f32x4 c) {
  return __builtin_amdgcn_mfma_f32_16x16x32_bf16(a, b, c, 0, 0, 0);
}

// ---- pack hidden (B,T,P,D) f32 -> xb (B,P,T,D) bf16 ----------------------
__global__ __launch_bounds__(256) void conv_x(const float* __restrict__ hs,
                                              unsigned short* __restrict__ xb) {
  int gid = blockIdx.x * 256 + threadIdx.x;
  size_t e = (size_t)gid * 4;
  int r = (int)(e >> 10);          // bp*512 + t
  int d = (int)(e & 1023);
  int b = r >> 12, p = (r >> 9) & 7, t = r & 511;
  const float4* src = (const float4*)(hs + ((((size_t)b * 512 + t) * 8 + p) << 10) + d);
  float4 v = *src;
  us4 o;
  o.x = f2bf(v.x); o.y = f2bf(v.y); o.z = f2bf(v.z); o.w = f2bf(v.w);
  *(us4*)(xb + e) = o;
}

// ---- W (C=1024, N) f32 -> Wt (N, 1024) bf16 (transposed) -----------------
__global__ __launch_bounds__(256) void conv_wt(const float* __restrict__ W,
                                               unsigned short* __restrict__ Wt, int N) {
  int gid = blockIdx.x * 256 + threadIdx.x;   // N*1024 threads
  int c = gid & 1023;
  int n = gid >> 10;
  Wt[(size_t)n * 1024 + c] = f2bf(W[(size_t)c * N + n]);
}

// ---- in-place RoPE on (bp, t, H*64) bf16 ---------------------------------
template <int H, int LH>
__global__ __launch_bounds__(256) void rope_k(unsigned short* __restrict__ buf) {
  int gid = blockIdx.x * 256 + threadIdx.x;   // BP*T*H*32 threads
  int d = gid & 31;
  int h = (gid >> 5) & (H - 1);
  int rt = gid >> (5 + LH);                    // bp*512 + t
  int t = rt & 511;
  size_t base = (((size_t)rt) * H + h) * 64 + d;
  float x1 = bf2f(buf[base]);
  float x2 = bf2f(buf[base + 32]);
  // inv_freq = 10000^{-d/32} = exp2(-d * log2(10000)/32)
  float ang = (float)t * exp2f((float)d * -0.41524101186092029f);
  float s, c;
  sincosf(ang, &s, &c);
  buf[base]      = f2bf(x1 * c - x2 * s);
  buf[base + 32] = f2bf(x1 * s + x2 * c);
}

// ---- 128x128x(K=1024) bf16 GEMM, B^T input, m97-style staging ------------
// MODE 0: QKV projection. cols 0..1023 -> qb (row-major), 1024..1279 -> kb,
//         1280..1535 -> vtb TRANSPOSED ((bp,h,d),t).
// MODE 1: O projection. writes fp32 out[(b,t,p),col].
template <int NT, int MODE>
__global__ __launch_bounds__(256) void gemm_bt(
    const unsigned short* __restrict__ A, const unsigned short* __restrict__ Bt,
    unsigned short* __restrict__ qb, unsigned short* __restrict__ kb,
    unsigned short* __restrict__ vtb, float* __restrict__ out) {
  constexpr int K = 1024;
  __shared__ __align__(16) unsigned short As[128 * 64];
  __shared__ __align__(16) unsigned short Bs[128 * 64];

  int tid = threadIdx.x;
  int lane = tid & 63, wid = tid >> 6;
  int quad = lane >> 4, lo = lane & 15;
  int tn = blockIdx.x % NT, tm = blockIdx.x / NT;
  int wm = (wid >> 1) * 64, wn = (wid & 1) * 64;
  int srow = lane >> 3, schunk = lane & 7;

  f32x4 z = {0.f, 0.f, 0.f, 0.f};
  f32x4 acc[4][4];
  for (int i = 0; i < 4; ++i) for (int j = 0; j < 4; ++j) acc[i][j] = z;

  const unsigned short* Ab = A + (size_t)(tm * 128) * K;
  const unsigned short* Bb = Bt + (size_t)(tn * 128) * K;

  for (int k0 = 0; k0 < K; k0 += 64) {
    __syncthreads();
    // stage 128 rows x 64 bf16 for A and B; XOR-swizzle on the GLOBAL side
    // (LDS dest is forced to base + lane*16 by global_load_lds).
    for (int i = 0; i < 4; ++i) {
      int row = wid * 8 + i * 32 + srow;
      int cg = schunk ^ (row & 7);
      ld_lds16(Ab + (size_t)row * K + k0 + cg * 8, (char*)As + (wid * 8 + i * 32) * 128);
      ld_lds16(Bb + (size_t)row * K + k0 + cg * 8, (char*)Bs + (wid * 8 + i * 32) * 128);
    }
    __syncthreads();
#pragma unroll
    for (int kk = 0; kk < 64; kk += 32) {
      bf16x8 af[4], bb[4];
#pragma unroll
      for (int mi = 0; mi < 4; ++mi) {
        int row = wm + mi * 16 + lo;
        int cg = (quad + (kk >> 3)) ^ (row & 7);
        af[mi] = *(const bf16x8*)(As + (size_t)row * 64 + cg * 8);
      }
#pragma unroll
      for (int ni = 0; ni < 4; ++ni) {
        int row = wn + ni * 16 + lo;
        int cg = (quad + (kk >> 3)) ^ (row & 7);
        bb[ni] = *(const bf16x8*)(Bs + (size_t)row * 64 + cg * 8);
      }
#pragma unroll
      for (int mi = 0; mi < 4; ++mi)
#pragma unroll
        for (int ni = 0; ni < 4; ++ni)
          acc[mi][ni] = mfma16(af[mi], bb[ni], acc[mi][ni]);
    }
  }

  // epilogue: C/D layout col = lane&15, row = quad*4 + reg  [m89/m91]
  for (int mi = 0; mi < 4; ++mi) {
    for (int ni = 0; ni < 4; ++ni) {
      int col = tn * 128 + wn + ni * 16 + lo;
      for (int r = 0; r < 4; ++r) {
        int grow = tm * 128 + wm + mi * 16 + quad * 4 + r;
        float val = acc[mi][ni][r];
        if (MODE == 0) {
          if (col < 1024) {
            qb[(size_t)grow * 1024 + col] = f2bf(val);
          } else if (col < 1280) {
            kb[(size_t)grow * 256 + (col - 1024)] = f2bf(val);
          } else {
            int cc = col - 1280;
            int hh = cc >> 6, dd = cc & 63;
            int bp = grow >> 9, t = grow & 511;
            vtb[(((size_t)(bp * 4 + hh)) * 64 + dd) * 512 + t] = f2bf(val);
          }
        } else {
          int bp = grow >> 9, t = grow & 511;
          int b = bp >> 3, p = bp & 7;
          out[((((size_t)b * 512 + t) * 8 + p) << 10) + col] = val;
        }
      }
    }
  }
}

// ---- flash attention: block = (bp, h, q-tile of 128); 4 waves x 32 q-rows
__global__ __launch_bounds__(256) void attn(
    const unsigned short* __restrict__ qb, const unsigned short* __restrict__ kb,
    const unsigned short* __restrict__ vtb, unsigned short* __restrict__ ao) {
  __shared__ __align__(16) unsigned short Qs[128 * 64];
  __shared__ __align__(16) unsigned short Ks[64 * 64];
  __shared__ __align__(16) unsigned short Vs[64 * 64];       // V^T: [d][key]
  __shared__ __align__(16) unsigned short Ps[4][32 * 72];    // per-wave P, pad 72

  int tid = threadIdx.x;
  int lane = tid & 63, wid = tid >> 6;
  int quad = lane >> 4, lo = lane & 15;
  int qt = blockIdx.x & 3, bph = blockIdx.x >> 2;
  int h = bph & 15, bp = bph >> 4;
  int kvh = h >> 2;
  int t0 = qt * 128;
  int srow = lane >> 3, schunk = lane & 7;

  const unsigned short* qg = qb + ((size_t)(bp * 512 + t0)) * 1024 + h * 64;
  const unsigned short* kg = kb + ((size_t)bp * 512) * 256 + kvh * 64;
  const unsigned short* vg = vtb + ((size_t)(bp * 4 + kvh)) * 64 * 512;

  for (int i = 0; i < 4; ++i) {    // stage Q once: 128 rows x 128B
    int row = wid * 8 + i * 32 + srow;
    int cg = schunk ^ (row & 7);
    ld_lds16(qg + (size_t)row * 1024 + cg * 8, (char*)Qs + (wid * 8 + i * 32) * 128);
  }

  f32x4 z = {0.f, 0.f, 0.f, 0.f};
  f32x4 oacc[2][4];
  for (int i = 0; i < 2; ++i) for (int j = 0; j < 4; ++j) oacc[i][j] = z;
  float mrow[2][4], lrow[2][4];
  for (int i = 0; i < 2; ++i)
    for (int r = 0; r < 4; ++r) { mrow[i][r] = -1e30f; lrow[i][r] = 0.f; }

  for (int kt = 0; kt < 512; kt += 64) {
    __syncthreads();
    for (int i = 0; i < 2; ++i) {  // stage 64 keys of K and V^T
      int row = wid * 8 + i * 32 + srow;
      int cg = schunk ^ (row & 7);
      ld_lds16(kg + (size_t)(kt + row) * 256 + cg * 8, (char*)Ks + (wid * 8 + i * 32) * 128);
      ld_lds16(vg + (size_t)row * 512 + kt + cg * 8, (char*)Vs + (wid * 8 + i * 32) * 128);
    }
    __syncthreads();

    f32x4 sacc[2][4];
    for (int i = 0; i < 2; ++i) for (int j = 0; j < 4; ++j) sacc[i][j] = z;
#pragma unroll
    for (int kk = 0; kk < 64; kk += 32) {
      bf16x8 aq[2], bk[4];
#pragma unroll
      for (int mi = 0; mi < 2; ++mi) {
        int row = wid * 32 + mi * 16 + lo;
        int cg = (quad + (kk >> 3)) ^ (row & 7);
        aq[mi] = *(const bf16x8*)(Qs + (size_t)row * 64 + cg * 8);
      }
#pragma unroll
      for (int ni = 0; ni < 4; ++ni) {
        int row = ni * 16 + lo;
        int cg = (quad + (kk >> 3)) ^ (row & 7);
        bk[ni] = *(const bf16x8*)(Ks + (size_t)row * 64 + cg * 8);
      }
#pragma unroll
      for (int mi = 0; mi < 2; ++mi)
#pragma unroll
        for (int ni = 0; ni < 4; ++ni)
          sacc[mi][ni] = mfma16(aq[mi], bk[ni], sacc[mi][ni]);
    }

    // online softmax (scale 1/sqrt(64)=0.125 folded at exp time)
#pragma unroll
    for (int mi = 0; mi < 2; ++mi) {
#pragma unroll
      for (int r = 0; r < 4; ++r) {
        float mx = fmaxf(fmaxf(sacc[mi][0][r], sacc[mi][1][r]),
                         fmaxf(sacc[mi][2][r], sacc[mi][3][r]));
        mx = fmaxf(mx, __shfl_xor(mx, 1));
        mx = fmaxf(mx, __shfl_xor(mx, 2));
        mx = fmaxf(mx, __shfl_xor(mx, 4));
        mx = fmaxf(mx, __shfl_xor(mx, 8));
        mx *= 0.125f;
        float mold = mrow[mi][r];
        float mnew = fmaxf(mold, mx);
        float alpha = __expf(mold - mnew);
        float sum = 0.f;
#pragma unroll
        for (int ni = 0; ni < 4; ++ni) {
          float pv = __expf(sacc[mi][ni][r] * 0.125f - mnew);
          sacc[mi][ni][r] = pv;
          sum += pv;
        }
        sum += __shfl_xor(sum, 1);
        sum += __shfl_xor(sum, 2);
        sum += __shfl_xor(sum, 4);
        sum += __shfl_xor(sum, 8);
        lrow[mi][r] = lrow[mi][r] * alpha + sum;
        mrow[mi][r] = mnew;
#pragma unroll
        for (int ni = 0; ni < 4; ++ni) oacc[mi][ni][r] *= alpha;
      }
    }

    // P: C-layout -> A-layout via per-wave LDS round-trip [m120]
    unsigned short* pw = &Ps[wid][0];
#pragma unroll
    for (int mi = 0; mi < 2; ++mi)
#pragma unroll
      for (int ni = 0; ni < 4; ++ni)
#pragma unroll
        for (int r = 0; r < 4; ++r) {
          int m = mi * 16 + quad * 4 + r;
          pw[m * 72 + ni * 16 + lo] = f2bf(sacc[mi][ni][r]);
        }

#pragma unroll
    for (int kk = 0; kk < 64; kk += 32) {
      bf16x8 ap[2], bv[4];
#pragma unroll
      for (int mi = 0; mi < 2; ++mi) {
        int m = mi * 16 + lo;
        ap[mi] = *(const bf16x8*)(pw + m * 72 + quad * 8 + kk);
      }
#pragma unroll
      for (int ni = 0; ni < 4; ++ni) {
        int d = ni * 16 + lo;
        int cg = (quad + (kk >> 3)) ^ (d & 7);
        bv[ni] = *(const bf16x8*)(Vs + (size_t)d * 64 + cg * 8);
      }
#pragma unroll
      for (int mi = 0; mi < 2; ++mi)
#pragma unroll
        for (int ni = 0; ni < 4; ++ni)
          oacc[mi][ni] = mfma16(ap[mi], bv[ni], oacc[mi][ni]);
    }
  }

  for (int mi = 0; mi < 2; ++mi)
    for (int ni = 0; ni < 4; ++ni)
      for (int r = 0; r < 4; ++r) {
        int trow = t0 + wid * 32 + mi * 16 + quad * 4 + r;
        float val = oacc[mi][ni][r] / lrow[mi][r];
        ao[((size_t)(bp * 512 + trow)) * 1024 + h * 64 + ni * 16 + lo] = f2bf(val);
      }
}

extern "C" void kernel_launch(void* const* d_in, const int* in_sizes, int n_in,
                              void* d_out, int out_size, void* d_ws, size_t ws_size,
                              hipStream_t stream) {
  const float* hs = (const float*)d_in[0];
  const float* Wq = (const float*)d_in[1];
  const float* Wk = (const float*)d_in[2];
  const float* Wv = (const float*)d_in[3];
  const float* Wo = (const float*)d_in[4];
  float* out = (float*)d_out;

  // workspace layout (bf16 elements); ao aliases xb (xb dead after QKV GEMM)
  unsigned short* xb   = (unsigned short*)d_ws;                 // 8192*1024
  unsigned short* wqkv = xb + (size_t)8192 * 1024;              // 1536*1024
  unsigned short* wot  = wqkv + (size_t)1536 * 1024;            // 1024*1024
  unsigned short* qbuf = wot + (size_t)1024 * 1024;             // 8192*1024
  unsigned short* kbuf = qbuf + (size_t)8192 * 1024;            // 8192*256
  unsigned short* vtb  = kbuf + (size_t)8192 * 256;             // 8192*256
  unsigned short* ao   = xb;                                    // alias (16 MB saved)

  conv_x<<<8192, 256, 0, stream>>>(hs, xb);
  conv_wt<<<4096, 256, 0, stream>>>(Wq, wqkv, 1024);
  conv_wt<<<1024, 256, 0, stream>>>(Wk, wqkv + (size_t)1024 * 1024, 256);
  conv_wt<<<1024, 256, 0, stream>>>(Wv, wqkv + (size_t)1280 * 1024, 256);
  conv_wt<<<4096, 256, 0, stream>>>(Wo, wot, 1024);
  gemm_bt<12, 0><<<768, 256, 0, stream>>>(xb, wqkv, qbuf, kbuf, vtb, nullptr);
  rope_k<16, 4><<<16384, 256, 0, stream>>>(qbuf);
  rope_k<4, 2><<<4096, 256, 0, stream>>>(kbuf);
  attn<<<1024, 256, 0, stream>>>(qbuf, kbuf, vtb, ao);
  gemm_bt<8, 1><<<512, 256, 0, stream>>>(ao, wot, nullptr, nullptr, nullptr, out);
}

// Round 2
// 244.486 us; speedup vs baseline: 1.5558x; 1.5558x over previous
//
#include <hip/hip_runtime.h>
#include <stdint.h>

// Problem constants: B=2, T=512, P=8, D=1024, NH=16, NKV=4, HD=64
// Rows (b,p,t): 16*512 = 8192.

typedef __attribute__((ext_vector_type(8))) short bf16x8;
typedef __attribute__((ext_vector_type(4))) float f32x4;
typedef __attribute__((ext_vector_type(4))) unsigned short us4;
typedef __attribute__((ext_vector_type(8))) unsigned short us8;

static __device__ __forceinline__ unsigned short f2bf(float f) {
  unsigned u = __float_as_uint(f);
  u += 0x7fffu + ((u >> 16) & 1u);   // RNE
  return (unsigned short)(u >> 16);
}
static __device__ __forceinline__ float bf2f(unsigned short s) {
  return __uint_as_float(((unsigned)s) << 16);
}

static __device__ __forceinline__ void ld_lds16(const void* g, void* l) {
  __builtin_amdgcn_global_load_lds(
      (const __attribute__((address_space(1))) void*)g,
      (__attribute__((address_space(3))) void*)l, 16, 0, 0);
}

static __device__ __forceinline__ f32x4 mfma16(bf16x8 a, bf16x8 b, f32x4 c) {
  return __builtin_amdgcn_mfma_f32_16x16x32_bf16(a, b, c, 0, 0, 0);
}

// ---- pack hidden (B,T,P,D) f32 -> xb (B,P,T,D) bf16 ----------------------
__global__ __launch_bounds__(256) void conv_x(const float* __restrict__ hs,
                                              unsigned short* __restrict__ xb) {
  int gid = blockIdx.x * 256 + threadIdx.x;
  size_t e = (size_t)gid * 4;
  int r = (int)(e >> 10);          // bp*512 + t
  int d = (int)(e & 1023);
  int b = r >> 12, p = (r >> 9) & 7, t = r & 511;
  const float4* src = (const float4*)(hs + ((((size_t)b * 512 + t) * 8 + p) << 10) + d);
  float4 v = *src;
  us4 o;
  o.x = f2bf(v.x); o.y = f2bf(v.y); o.z = f2bf(v.z); o.w = f2bf(v.w);
  *(us4*)(xb + e) = o;
}

// ---- W (C=1024, N) f32 -> Wt (N, 1024) bf16 (transposed) -----------------
__global__ __launch_bounds__(256) void conv_wt(const float* __restrict__ W,
                                               unsigned short* __restrict__ Wt, int N) {
  int gid = blockIdx.x * 256 + threadIdx.x;   // N*1024 threads
  int c = gid & 1023;
  int n = gid >> 10;
  Wt[(size_t)n * 1024 + c] = f2bf(W[(size_t)c * N + n]);
}

// ---- 128x128x(K=1024) bf16 GEMM, B^T input, m97-style staging ------------
// MODE 0: QKV projection, RoPE fused for Q/K blocks.
//         tn 0..7  -> qb row-major (rope'd)
//         tn 8..9  -> kb row-major (rope'd)
//         tn 10..11-> vtb TRANSPOSED ((bp,kvh,d),t)
// MODE 1: O projection. writes fp32 out[(b,t,p),col].
template <int NT, int MODE>
__global__ __launch_bounds__(256) void gemm_bt(
    const unsigned short* __restrict__ A, const unsigned short* __restrict__ Bt,
    unsigned short* __restrict__ qb, unsigned short* __restrict__ kb,
    unsigned short* __restrict__ vtb, float* __restrict__ out) {
  constexpr int K = 1024;
  __shared__ __align__(16) unsigned short Sm[128 * 128];   // As | Bs, reused as Cs
  unsigned short* As = Sm;
  unsigned short* Bs = Sm + 128 * 64;
  unsigned short* Cs = Sm;

  int tid = threadIdx.x;
  int lane = tid & 63, wid = tid >> 6;
  int quad = lane >> 4, lo = lane & 15;
  int tn = blockIdx.x % NT, tm = blockIdx.x / NT;
  int wm = (wid >> 1) * 64, wn = (wid & 1) * 64;
  int srow = lane >> 3, schunk = lane & 7;

  f32x4 z = {0.f, 0.f, 0.f, 0.f};
  f32x4 acc[4][4];
  for (int i = 0; i < 4; ++i) for (int j = 0; j < 4; ++j) acc[i][j] = z;

  const unsigned short* Ab = A + (size_t)(tm * 128) * K;
  const unsigned short* Bb = Bt + (size_t)(tn * 128) * K;

  for (int k0 = 0; k0 < K; k0 += 64) {
    __syncthreads();
    // stage 128 rows x 64 bf16 for A and B; XOR-swizzle on the GLOBAL side
    // (LDS dest is forced to base + lane*16 by global_load_lds).
    for (int i = 0; i < 4; ++i) {
      int row = wid * 8 + i * 32 + srow;
      int cg = schunk ^ (row & 7);
      ld_lds16(Ab + (size_t)row * K + k0 + cg * 8, (char*)As + (wid * 8 + i * 32) * 128);
      ld_lds16(Bb + (size_t)row * K + k0 + cg * 8, (char*)Bs + (wid * 8 + i * 32) * 128);
    }
    __syncthreads();
#pragma unroll
    for (int kk = 0; kk < 64; kk += 32) {
      bf16x8 af[4], bb[4];
#pragma unroll
      for (int mi = 0; mi < 4; ++mi) {
        int row = wm + mi * 16 + lo;
        int cg = (quad + (kk >> 3)) ^ (row & 7);
        af[mi] = *(const bf16x8*)(As + (size_t)row * 64 + cg * 8);
      }
#pragma unroll
      for (int ni = 0; ni < 4; ++ni) {
        int row = wn + ni * 16 + lo;
        int cg = (quad + (kk >> 3)) ^ (row & 7);
        bb[ni] = *(const bf16x8*)(Bs + (size_t)row * 64 + cg * 8);
      }
#pragma unroll
      for (int mi = 0; mi < 4; ++mi)
#pragma unroll
        for (int ni = 0; ni < 4; ++ni)
          acc[mi][ni] = mfma16(af[mi], bb[ni], acc[mi][ni]);
    }
  }

  __syncthreads();   // all waves done reading As/Bs before Cs reuse

  // epilogue: C/D layout col = lane&15, row = quad*4 + reg  [m89/m91]
  if (MODE == 0 && tn < 10) {
    // --- fused RoPE: head-local d = ni*16+lo for ni<2, pair in ni+2 ------
#pragma unroll
    for (int mi = 0; mi < 4; ++mi)
#pragma unroll
      for (int r = 0; r < 4; ++r) {
        int t = (tm * 128 + wm + mi * 16 + quad * 4 + r) & 511;
#pragma unroll
        for (int ni = 0; ni < 2; ++ni) {
          float inv = exp2f((float)(ni * 16 + lo) * -0.41524101186092029f);
          float ang = (float)t * inv;
          float s, c;
          __sincosf(ang, &s, &c);
          float x1 = acc[mi][ni][r], x2 = acc[mi][ni + 2][r];
          acc[mi][ni][r]     = x1 * c - x2 * s;
          acc[mi][ni + 2][r] = x1 * s + x2 * c;
        }
      }
    // --- stage C-tile to LDS (XOR swizzle on 8-elem chunks) --------------
#pragma unroll
    for (int mi = 0; mi < 4; ++mi)
#pragma unroll
      for (int ni = 0; ni < 4; ++ni)
#pragma unroll
        for (int r = 0; r < 4; ++r) {
          int row = wm + mi * 16 + quad * 4 + r;
          int col = wn + ni * 16 + lo;
          int cs = col ^ (((row >> 2) & 3) << 3);
          Cs[row * 128 + cs] = f2bf(acc[mi][ni][r]);
        }
    __syncthreads();
    // --- wide coalesced stores: 16 lanes x 16B = 256B contiguous ---------
    int tc = tid & 15, ro = tid >> 4;
#pragma unroll
    for (int it = 0; it < 8; ++it) {
      int row = ro + 16 * it;
      int cs = (tc * 8) ^ (((row >> 2) & 3) << 3);
      us8 v = *(const us8*)(Cs + row * 128 + cs);
      size_t grow = (size_t)(tm * 128 + row);
      if (tn < 8) {
        *(us8*)(qb + grow * 1024 + tn * 128 + tc * 8) = v;
      } else {
        *(us8*)(kb + grow * 256 + (tn - 8) * 128 + tc * 8) = v;
      }
    }
  } else {
    for (int mi = 0; mi < 4; ++mi) {
      for (int ni = 0; ni < 4; ++ni) {
        int col = tn * 128 + wn + ni * 16 + lo;
        for (int r = 0; r < 4; ++r) {
          int grow = tm * 128 + wm + mi * 16 + quad * 4 + r;
          float val = acc[mi][ni][r];
          if (MODE == 0) {
            // V block: cc = col-1280, transposed store
            int cc = col - 1280;
            int hh = cc >> 6, dd = cc & 63;
            int bp = grow >> 9, t = grow & 511;
            vtb[(((size_t)(bp * 4 + hh)) * 64 + dd) * 512 + t] = f2bf(val);
          } else {
            int bp = grow >> 9, t = grow & 511;
            int b = bp >> 3, p = bp & 7;
            out[((((size_t)b * 512 + t) * 8 + p) << 10) + col] = val;
          }
        }
      }
    }
  }
}

// ---- flash attention: block = (bp, h, q-tile of 128); 4 waves x 32 q-rows
__global__ __launch_bounds__(256) void attn(
    const unsigned short* __restrict__ qb, const unsigned short* __restrict__ kb,
    const unsigned short* __restrict__ vtb, unsigned short* __restrict__ ao) {
  __shared__ __align__(16) unsigned short Qs[128 * 64];
  __shared__ __align__(16) unsigned short Ks[64 * 64];
  __shared__ __align__(16) unsigned short Vs[64 * 64];       // V^T: [d][key]
  __shared__ __align__(16) unsigned short Ps[4][32 * 72];    // per-wave P, pad 72

  int tid = threadIdx.x;
  int lane = tid & 63, wid = tid >> 6;
  int quad = lane >> 4, lo = lane & 15;
  int qt = blockIdx.x & 3, bph = blockIdx.x >> 2;
  int h = bph & 15, bp = bph >> 4;
  int kvh = h >> 2;
  int t0 = qt * 128;
  int srow = lane >> 3, schunk = lane & 7;

  const unsigned short* qg = qb + ((size_t)(bp * 512 + t0)) * 1024 + h * 64;
  const unsigned short* kg = kb + ((size_t)bp * 512) * 256 + kvh * 64;
  const unsigned short* vg = vtb + ((size_t)(bp * 4 + kvh)) * 64 * 512;

  for (int i = 0; i < 4; ++i) {    // stage Q once: 128 rows x 128B
    int row = wid * 8 + i * 32 + srow;
    int cg = schunk ^ (row & 7);
    ld_lds16(qg + (size_t)row * 1024 + cg * 8, (char*)Qs + (wid * 8 + i * 32) * 128);
  }

  f32x4 z = {0.f, 0.f, 0.f, 0.f};
  f32x4 oacc[2][4];
  for (int i = 0; i < 2; ++i) for (int j = 0; j < 4; ++j) oacc[i][j] = z;
  float mrow[2][4], lrow[2][4];
  for (int i = 0; i < 2; ++i)
    for (int r = 0; r < 4; ++r) { mrow[i][r] = -1e30f; lrow[i][r] = 0.f; }

  for (int kt = 0; kt < 512; kt += 64) {
    __syncthreads();
    for (int i = 0; i < 2; ++i) {  // stage 64 keys of K and V^T
      int row = wid * 8 + i * 32 + srow;
      int cg = schunk ^ (row & 7);
      ld_lds16(kg + (size_t)(kt + row) * 256 + cg * 8, (char*)Ks + (wid * 8 + i * 32) * 128);
      ld_lds16(vg + (size_t)row * 512 + kt + cg * 8, (char*)Vs + (wid * 8 + i * 32) * 128);
    }
    __syncthreads();

    f32x4 sacc[2][4];
    for (int i = 0; i < 2; ++i) for (int j = 0; j < 4; ++j) sacc[i][j] = z;
#pragma unroll
    for (int kk = 0; kk < 64; kk += 32) {
      bf16x8 aq[2], bk[4];
#pragma unroll
      for (int mi = 0; mi < 2; ++mi) {
        int row = wid * 32 + mi * 16 + lo;
        int cg = (quad + (kk >> 3)) ^ (row & 7);
        aq[mi] = *(const bf16x8*)(Qs + (size_t)row * 64 + cg * 8);
      }
#pragma unroll
      for (int ni = 0; ni < 4; ++ni) {
        int row = ni * 16 + lo;
        int cg = (quad + (kk >> 3)) ^ (row & 7);
        bk[ni] = *(const bf16x8*)(Ks + (size_t)row * 64 + cg * 8);
      }
#pragma unroll
      for (int mi = 0; mi < 2; ++mi)
#pragma unroll
        for (int ni = 0; ni < 4; ++ni)
          sacc[mi][ni] = mfma16(aq[mi], bk[ni], sacc[mi][ni]);
    }

    // online softmax (scale 1/sqrt(64)=0.125 folded at exp time)
#pragma unroll
    for (int mi = 0; mi < 2; ++mi) {
#pragma unroll
      for (int r = 0; r < 4; ++r) {
        float mx = fmaxf(fmaxf(sacc[mi][0][r], sacc[mi][1][r]),
                         fmaxf(sacc[mi][2][r], sacc[mi][3][r]));
        mx = fmaxf(mx, __shfl_xor(mx, 1));
        mx = fmaxf(mx, __shfl_xor(mx, 2));
        mx = fmaxf(mx, __shfl_xor(mx, 4));
        mx = fmaxf(mx, __shfl_xor(mx, 8));
        mx *= 0.125f;
        float mold = mrow[mi][r];
        float mnew = fmaxf(mold, mx);
        float alpha = __expf(mold - mnew);
        float sum = 0.f;
#pragma unroll
        for (int ni = 0; ni < 4; ++ni) {
          float pv = __expf(sacc[mi][ni][r] * 0.125f - mnew);
          sacc[mi][ni][r] = pv;
          sum += pv;
        }
        sum += __shfl_xor(sum, 1);
        sum += __shfl_xor(sum, 2);
        sum += __shfl_xor(sum, 4);
        sum += __shfl_xor(sum, 8);
        lrow[mi][r] = lrow[mi][r] * alpha + sum;
        mrow[mi][r] = mnew;
#pragma unroll
        for (int ni = 0; ni < 4; ++ni) oacc[mi][ni][r] *= alpha;
      }
    }

    // P: C-layout -> A-layout via per-wave LDS round-trip [m120]
    unsigned short* pw = &Ps[wid][0];
#pragma unroll
    for (int mi = 0; mi < 2; ++mi)
#pragma unroll
      for (int ni = 0; ni < 4; ++ni)
#pragma unroll
        for (int r = 0; r < 4; ++r) {
          int m = mi * 16 + quad * 4 + r;
          pw[m * 72 + ni * 16 + lo] = f2bf(sacc[mi][ni][r]);
        }

#pragma unroll
    for (int kk = 0; kk < 64; kk += 32) {
      bf16x8 ap[2], bv[4];
#pragma unroll
      for (int mi = 0; mi < 2; ++mi) {
        int m = mi * 16 + lo;
        ap[mi] = *(const bf16x8*)(pw + m * 72 + quad * 8 + kk);
      }
#pragma unroll
      for (int ni = 0; ni < 4; ++ni) {
        int d = ni * 16 + lo;
        int cg = (quad + (kk >> 3)) ^ (d & 7);
        bv[ni] = *(const bf16x8*)(Vs + (size_t)d * 64 + cg * 8);
      }
#pragma unroll
      for (int mi = 0; mi < 2; ++mi)
#pragma unroll
        for (int ni = 0; ni < 4; ++ni)
          oacc[mi][ni] = mfma16(ap[mi], bv[ni], oacc[mi][ni]);
    }
  }

  for (int mi = 0; mi < 2; ++mi)
    for (int ni = 0; ni < 4; ++ni)
      for (int r = 0; r < 4; ++r) {
        int trow = t0 + wid * 32 + mi * 16 + quad * 4 + r;
        float val = oacc[mi][ni][r] / lrow[mi][r];
        ao[((size_t)(bp * 512 + trow)) * 1024 + h * 64 + ni * 16 + lo] = f2bf(val);
      }
}

extern "C" void kernel_launch(void* const* d_in, const int* in_sizes, int n_in,
                              void* d_out, int out_size, void* d_ws, size_t ws_size,
                              hipStream_t stream) {
  const float* hs = (const float*)d_in[0];
  const float* Wq = (const float*)d_in[1];
  const float* Wk = (const float*)d_in[2];
  const float* Wv = (const float*)d_in[3];
  const float* Wo = (const float*)d_in[4];
  float* out = (float*)d_out;

  // workspace layout (bf16 elements); ao aliases xb (xb dead after QKV GEMM)
  unsigned short* xb   = (unsigned short*)d_ws;                 // 8192*1024
  unsigned short* wqkv = xb + (size_t)8192 * 1024;              // 1536*1024
  unsigned short* wot  = wqkv + (size_t)1536 * 1024;            // 1024*1024
  unsigned short* qbuf = wot + (size_t)1024 * 1024;             // 8192*1024
  unsigned short* kbuf = qbuf + (size_t)8192 * 1024;            // 8192*256
  unsigned short* vtb  = kbuf + (size_t)8192 * 256;             // 8192*256
  unsigned short* ao   = xb;                                    // alias (16 MB saved)

  conv_x<<<8192, 256, 0, stream>>>(hs, xb);
  conv_wt<<<4096, 256, 0, stream>>>(Wq, wqkv, 1024);
  conv_wt<<<1024, 256, 0, stream>>>(Wk, wqkv + (size_t)1024 * 1024, 256);
  conv_wt<<<1024, 256, 0, stream>>>(Wv, wqkv + (size_t)1280 * 1024, 256);
  conv_wt<<<4096, 256, 0, stream>>>(Wo, wot, 1024);
  gemm_bt<12, 0><<<768, 256, 0, stream>>>(xb, wqkv, qbuf, kbuf, vtb, nullptr);
  attn<<<1024, 256, 0, stream>>>(qbuf, kbuf, vtb, ao);
  gemm_bt<8, 1><<<512, 256, 0, stream>>>(ao, wot, nullptr, nullptr, nullptr, out);
}

// Round 3
// 210.215 us; speedup vs baseline: 1.8095x; 1.1630x over previous
//
#include <hip/hip_runtime.h>
#include <stdint.h>

// Problem constants: B=2, T=512, P=8, D=1024, NH=16, NKV=4, HD=64
// Rows (b,p,t): 16*512 = 8192.

typedef __attribute__((ext_vector_type(8))) short bf16x8;
typedef __attribute__((ext_vector_type(4))) float f32x4;
typedef __attribute__((ext_vector_type(16))) float f32x16;
typedef __attribute__((ext_vector_type(4))) unsigned short us4;
typedef __attribute__((ext_vector_type(8))) unsigned short us8;

static __device__ __forceinline__ unsigned short f2bf(float f) {
  unsigned u = __float_as_uint(f);
  u += 0x7fffu + ((u >> 16) & 1u);   // RNE
  return (unsigned short)(u >> 16);
}
static __device__ __forceinline__ float bf2f(unsigned short s) {
  return __uint_as_float(((unsigned)s) << 16);
}

static __device__ __forceinline__ void ld_lds16(const void* g, void* l) {
  __builtin_amdgcn_global_load_lds(
      (const __attribute__((address_space(1))) void*)g,
      (__attribute__((address_space(3))) void*)l, 16, 0, 0);
}

static __device__ __forceinline__ f32x4 mfma16(bf16x8 a, bf16x8 b, f32x4 c) {
  return __builtin_amdgcn_mfma_f32_16x16x32_bf16(a, b, c, 0, 0, 0);
}
static __device__ __forceinline__ f32x16 mfma32(bf16x8 a, bf16x8 b, f32x16 c) {
  return __builtin_amdgcn_mfma_f32_32x32x16_bf16(a, b, c, 0, 0, 0);
}

// ---- pack hidden (B,T,P,D) f32 -> xb (B,P,T,D) bf16 ----------------------
__global__ __launch_bounds__(256) void conv_x(const float* __restrict__ hs,
                                              unsigned short* __restrict__ xb) {
  int gid = blockIdx.x * 256 + threadIdx.x;
  size_t e = (size_t)gid * 4;
  int r = (int)(e >> 10);          // bp*512 + t
  int d = (int)(e & 1023);
  int b = r >> 12, p = (r >> 9) & 7, t = r & 511;
  const float4* src = (const float4*)(hs + ((((size_t)b * 512 + t) * 8 + p) << 10) + d);
  float4 v = *src;
  us4 o;
  o.x = f2bf(v.x); o.y = f2bf(v.y); o.z = f2bf(v.z); o.w = f2bf(v.w);
  *(us4*)(xb + e) = o;
}

// ---- W (C=1024, N) f32 -> Wt (N, 1024) bf16 (transposed) -----------------
__global__ __launch_bounds__(256) void conv_wt(const float* __restrict__ W,
                                               unsigned short* __restrict__ Wt, int N) {
  int gid = blockIdx.x * 256 + threadIdx.x;   // N*1024 threads
  int c = gid & 1023;
  int n = gid >> 10;
  Wt[(size_t)n * 1024 + c] = f2bf(W[(size_t)c * N + n]);
}

// ---- 128x128x(K=1024) bf16 GEMM, B^T input, m97-style staging ------------
// MODE 0: QKV projection, RoPE fused for Q/K blocks; Q scaled by 0.125.
//         tn 0..7  -> qb row-major (rope'd, *0.125)
//         tn 8..9  -> kb row-major (rope'd)
//         tn 10..11-> vtb TRANSPOSED ((bp,kvh,d),t)
// MODE 1: O projection. writes fp32 out[(b,t,p),col].
template <int NT, int MODE>
__global__ __launch_bounds__(256) void gemm_bt(
    const unsigned short* __restrict__ A, const unsigned short* __restrict__ Bt,
    unsigned short* __restrict__ qb, unsigned short* __restrict__ kb,
    unsigned short* __restrict__ vtb, float* __restrict__ out) {
  constexpr int K = 1024;
  __shared__ __align__(16) unsigned short Sm[128 * 128];   // As | Bs, reused as Cs
  unsigned short* As = Sm;
  unsigned short* Bs = Sm + 128 * 64;
  unsigned short* Cs = Sm;

  int tid = threadIdx.x;
  int lane = tid & 63, wid = tid >> 6;
  int quad = lane >> 4, lo = lane & 15;
  int tn = blockIdx.x % NT, tm = blockIdx.x / NT;
  int wm = (wid >> 1) * 64, wn = (wid & 1) * 64;
  int srow = lane >> 3, schunk = lane & 7;

  f32x4 z = {0.f, 0.f, 0.f, 0.f};
  f32x4 acc[4][4];
  for (int i = 0; i < 4; ++i) for (int j = 0; j < 4; ++j) acc[i][j] = z;

  const unsigned short* Ab = A + (size_t)(tm * 128) * K;
  const unsigned short* Bb = Bt + (size_t)(tn * 128) * K;

  for (int k0 = 0; k0 < K; k0 += 64) {
    __syncthreads();
    for (int i = 0; i < 4; ++i) {
      int row = wid * 8 + i * 32 + srow;
      int cg = schunk ^ (row & 7);
      ld_lds16(Ab + (size_t)row * K + k0 + cg * 8, (char*)As + (wid * 8 + i * 32) * 128);
      ld_lds16(Bb + (size_t)row * K + k0 + cg * 8, (char*)Bs + (wid * 8 + i * 32) * 128);
    }
    __syncthreads();
#pragma unroll
    for (int kk = 0; kk < 64; kk += 32) {
      bf16x8 af[4], bb[4];
#pragma unroll
      for (int mi = 0; mi < 4; ++mi) {
        int row = wm + mi * 16 + lo;
        int cg = (quad + (kk >> 3)) ^ (row & 7);
        af[mi] = *(const bf16x8*)(As + (size_t)row * 64 + cg * 8);
      }
#pragma unroll
      for (int ni = 0; ni < 4; ++ni) {
        int row = wn + ni * 16 + lo;
        int cg = (quad + (kk >> 3)) ^ (row & 7);
        bb[ni] = *(const bf16x8*)(Bs + (size_t)row * 64 + cg * 8);
      }
#pragma unroll
      for (int mi = 0; mi < 4; ++mi)
#pragma unroll
        for (int ni = 0; ni < 4; ++ni)
          acc[mi][ni] = mfma16(af[mi], bb[ni], acc[mi][ni]);
    }
  }

  __syncthreads();   // all waves done reading As/Bs before Cs reuse

  // epilogue: C/D layout col = lane&15, row = quad*4 + reg  [m89/m91]
  if (MODE == 0 && tn < 10) {
    float qscale = (tn < 8) ? 0.125f : 1.0f;   // fold 1/sqrt(HD) into Q
#pragma unroll
    for (int mi = 0; mi < 4; ++mi)
#pragma unroll
      for (int r = 0; r < 4; ++r) {
        int t = (tm * 128 + wm + mi * 16 + quad * 4 + r) & 511;
#pragma unroll
        for (int ni = 0; ni < 2; ++ni) {
          float inv = exp2f((float)(ni * 16 + lo) * -0.41524101186092029f);
          float ang = (float)t * inv;
          float s, c;
          __sincosf(ang, &s, &c);
          float x1 = acc[mi][ni][r], x2 = acc[mi][ni + 2][r];
          acc[mi][ni][r]     = (x1 * c - x2 * s) * qscale;
          acc[mi][ni + 2][r] = (x1 * s + x2 * c) * qscale;
        }
      }
    // --- stage C-tile to LDS (XOR swizzle on 8-elem chunks) --------------
#pragma unroll
    for (int mi = 0; mi < 4; ++mi)
#pragma unroll
      for (int ni = 0; ni < 4; ++ni)
#pragma unroll
        for (int r = 0; r < 4; ++r) {
          int row = wm + mi * 16 + quad * 4 + r;
          int col = wn + ni * 16 + lo;
          int cs = col ^ (((row >> 2) & 3) << 3);
          Cs[row * 128 + cs] = f2bf(acc[mi][ni][r]);
        }
    __syncthreads();
    // --- wide coalesced stores: 16 lanes x 16B = 256B contiguous ---------
    int tc = tid & 15, ro = tid >> 4;
#pragma unroll
    for (int it = 0; it < 8; ++it) {
      int row = ro + 16 * it;
      int cs = (tc * 8) ^ (((row >> 2) & 3) << 3);
      us8 v = *(const us8*)(Cs + row * 128 + cs);
      size_t grow = (size_t)(tm * 128 + row);
      if (tn < 8) {
        *(us8*)(qb + grow * 1024 + tn * 128 + tc * 8) = v;
      } else {
        *(us8*)(kb + grow * 256 + (tn - 8) * 128 + tc * 8) = v;
      }
    }
  } else {
    for (int mi = 0; mi < 4; ++mi) {
      for (int ni = 0; ni < 4; ++ni) {
        int col = tn * 128 + wn + ni * 16 + lo;
        for (int r = 0; r < 4; ++r) {
          int grow = tm * 128 + wm + mi * 16 + quad * 4 + r;
          float val = acc[mi][ni][r];
          if (MODE == 0) {
            int cc = col - 1280;
            int hh = cc >> 6, dd = cc & 63;
            int bp = grow >> 9, t = grow & 511;
            vtb[(((size_t)(bp * 4 + hh)) * 64 + dd) * 512 + t] = f2bf(val);
          } else {
            int bp = grow >> 9, t = grow & 511;
            int b = bp >> 3, p = bp & 7;
            out[((((size_t)b * 512 + t) * 8 + p) << 10) + col] = val;
          }
        }
      }
    }
  }
}

// ---- attention v2: transposed-S 32x32x16 MFMA, fixed-max softmax ---------
// block = (bp, head, q-tile of 128); 4 waves x 32 q-rows; 64-key tiles.
// S^T = mfma32(A=K, B=Q): C-layout row=key=(r&3)+8*(r>>2)+4*half, col=q=lane&31.
// P->A-operand needs only reg-pair pack + shfl_xor(32) + half select (no LDS).
__global__ __launch_bounds__(256, 4) void attn(
    const unsigned short* __restrict__ qb, const unsigned short* __restrict__ kb,
    const unsigned short* __restrict__ vtb, unsigned short* __restrict__ ao) {
  __shared__ __align__(16) unsigned short Qs[128 * 64];
  __shared__ __align__(16) unsigned short Ks[64 * 64];
  __shared__ __align__(16) unsigned short Vs[64 * 64];   // V^T: [d][key]

  int tid = threadIdx.x;
  int lane = tid & 63, wid = tid >> 6;
  int lo32 = lane & 31, hl = lane >> 5;
  int qt = blockIdx.x & 3, bph = blockIdx.x >> 2;
  int head = bph & 15, bp = bph >> 4;
  int kvh = head >> 2;
  int t0 = qt * 128;
  int srow = lane >> 3, schunk = lane & 7;

  const unsigned short* qg = qb + ((size_t)(bp * 512 + t0)) * 1024 + head * 64;
  const unsigned short* kg = kb + ((size_t)bp * 512) * 256 + kvh * 64;
  const unsigned short* vg = vtb + ((size_t)(bp * 4 + kvh)) * 64 * 512;

  for (int i = 0; i < 4; ++i) {    // stage Q once: 128 rows x 128B
    int row = wid * 8 + i * 32 + srow;
    int cg = schunk ^ (row & 7);
    ld_lds16(qg + (size_t)row * 1024 + cg * 8, (char*)Qs + (wid * 8 + i * 32) * 128);
  }

  f32x16 z16 = {0.f};
  f32x16 o0 = z16, o1 = z16;
  float psum = 0.f;
  int qrow = wid * 32 + lo32;

  for (int kt = 0; kt < 512; kt += 64) {
    __syncthreads();
    for (int i = 0; i < 2; ++i) {  // stage 64 keys of K and V^T
      int row = wid * 8 + i * 32 + srow;
      int cg = schunk ^ (row & 7);
      ld_lds16(kg + (size_t)(kt + row) * 256 + cg * 8, (char*)Ks + (wid * 8 + i * 32) * 128);
      ld_lds16(vg + (size_t)row * 512 + kt + cg * 8, (char*)Vs + (wid * 8 + i * 32) * 128);
    }
    __syncthreads();

    // S^T = K . Q^T over d=64 (4 chunks of K=16)
    f32x16 st0 = z16, st1 = z16;
#pragma unroll
    for (int kkc = 0; kkc < 4; ++kkc) {
      int ch = 2 * kkc + hl;
      bf16x8 qf = *(const bf16x8*)(Qs + (size_t)qrow * 64 + ((ch ^ (qrow & 7)) * 8));
      bf16x8 kf0 = *(const bf16x8*)(Ks + (size_t)lo32 * 64 + ((ch ^ (lo32 & 7)) * 8));
      bf16x8 kf1 = *(const bf16x8*)(Ks + (size_t)(32 + lo32) * 64 + ((ch ^ (lo32 & 7)) * 8));
      st0 = mfma32(kf0, qf, st0);
      st1 = mfma32(kf1, qf, st1);
    }

    // exp (no max subtraction; scale pre-folded into Q), pack, PV
#pragma unroll
    for (int t = 0; t < 2; ++t) {
      const f32x16& stv = t ? st1 : st0;
      unsigned pk[8], xpk[8];
#pragma unroll
      for (int p = 0; p < 8; ++p) {
        float e0 = __expf(stv[2 * p]);
        float e1 = __expf(stv[2 * p + 1]);
        psum += e0 + e1;
        pk[p] = ((__float_as_uint(e0) + 0x8000u) >> 16) |
                ((__float_as_uint(e1) + 0x8000u) & 0xffff0000u);
      }
#pragma unroll
      for (int p = 0; p < 8; ++p) xpk[p] = (unsigned)__shfl_xor((int)pk[p], 32);
#pragma unroll
      for (int cc = 0; cc < 2; ++cc) {
        int o = cc * 4;
        union { unsigned u[4]; bf16x8 v; } af;
        if (hl == 0) {
          af.u[0] = pk[o];      af.u[1] = pk[o + 1];
          af.u[2] = xpk[o];     af.u[3] = xpk[o + 1];
        } else {
          af.u[0] = xpk[o + 2]; af.u[1] = xpk[o + 3];
          af.u[2] = pk[o + 2];  af.u[3] = pk[o + 3];
        }
        int vch = 2 * (t * 2 + cc) + hl;
        bf16x8 v0 = *(const bf16x8*)(Vs + (size_t)lo32 * 64 + ((vch ^ (lo32 & 7)) * 8));
        bf16x8 v1 = *(const bf16x8*)(Vs + (size_t)(32 + lo32) * 64 + ((vch ^ (lo32 & 7)) * 8));
        o0 = mfma32(af.v, v0, o0);
        o1 = mfma32(af.v, v1, o1);
      }
    }
  }

  // normalize and store: D layout col=lane&31=d, row q_r=(r&3)+8*(r>>2)+4*hl
  psum += __shfl_xor(psum, 32);
  float inv = 1.f / psum;          // lane holds inv for q = lo32
#pragma unroll
  for (int r = 0; r < 16; ++r) {
    int q_r = (r & 3) + 8 * (r >> 2) + 4 * hl;
    float sc = __shfl(inv, q_r);   // holder lane q_r (lo32=q_r)
    size_t grow = (size_t)(bp * 512 + t0 + wid * 32 + q_r);
    ao[grow * 1024 + head * 64 + lo32]      = f2bf(o0[r] * sc);
    ao[grow * 1024 + head * 64 + 32 + lo32] = f2bf(o1[r] * sc);
  }
}

extern "C" void kernel_launch(void* const* d_in, const int* in_sizes, int n_in,
                              void* d_out, int out_size, void* d_ws, size_t ws_size,
                              hipStream_t stream) {
  const float* hs = (const float*)d_in[0];
  const float* Wq = (const float*)d_in[1];
  const float* Wk = (const float*)d_in[2];
  const float* Wv = (const float*)d_in[3];
  const float* Wo = (const float*)d_in[4];
  float* out = (float*)d_out;

  unsigned short* xb   = (unsigned short*)d_ws;                 // 8192*1024
  unsigned short* wqkv = xb + (size_t)8192 * 1024;              // 1536*1024
  unsigned short* wot  = wqkv + (size_t)1536 * 1024;            // 1024*1024
  unsigned short* qbuf = wot + (size_t)1024 * 1024;             // 8192*1024
  unsigned short* kbuf = qbuf + (size_t)8192 * 1024;            // 8192*256
  unsigned short* vtb  = kbuf + (size_t)8192 * 256;             // 8192*256
  unsigned short* ao   = xb;                                    // alias

  conv_x<<<8192, 256, 0, stream>>>(hs, xb);
  conv_wt<<<4096, 256, 0, stream>>>(Wq, wqkv, 1024);
  conv_wt<<<1024, 256, 0, stream>>>(Wk, wqkv + (size_t)1024 * 1024, 256);
  conv_wt<<<1024, 256, 0, stream>>>(Wv, wqkv + (size_t)1280 * 1024, 256);
  conv_wt<<<4096, 256, 0, stream>>>(Wo, wot, 1024);
  gemm_bt<12, 0><<<768, 256, 0, stream>>>(xb, wqkv, qbuf, kbuf, vtb, nullptr);
  attn<<<1024, 256, 0, stream>>>(qbuf, kbuf, vtb, ao);
  gemm_bt<8, 1><<<512, 256, 0, stream>>>(ao, wot, nullptr, nullptr, nullptr, out);
}

// Round 4
// 176.315 us; speedup vs baseline: 2.1574x; 1.1923x over previous
//
#include <hip/hip_runtime.h>
#include <stdint.h>

// Problem constants: B=2, T=512, P=8, D=1024, NH=16, NKV=4, HD=64
// Rows (b,p,t): 16*512 = 8192.

typedef __attribute__((ext_vector_type(8))) short bf16x8;
typedef __attribute__((ext_vector_type(4))) float f32x4;
typedef __attribute__((ext_vector_type(16))) float f32x16;
typedef __attribute__((ext_vector_type(4))) unsigned short us4;
typedef __attribute__((ext_vector_type(8))) unsigned short us8;

static __device__ __forceinline__ unsigned short f2bf(float f) {
  unsigned u = __float_as_uint(f);
  u += 0x7fffu + ((u >> 16) & 1u);   // RNE
  return (unsigned short)(u >> 16);
}

static __device__ __forceinline__ void ld_lds16(const void* g, void* l) {
  __builtin_amdgcn_global_load_lds(
      (const __attribute__((address_space(1))) void*)g,
      (__attribute__((address_space(3))) void*)l, 16, 0, 0);
}

static __device__ __forceinline__ f32x4 mfma16(bf16x8 a, bf16x8 b, f32x4 c) {
  return __builtin_amdgcn_mfma_f32_16x16x32_bf16(a, b, c, 0, 0, 0);
}
static __device__ __forceinline__ f32x16 mfma32(bf16x8 a, bf16x8 b, f32x16 c) {
  return __builtin_amdgcn_mfma_f32_32x32x16_bf16(a, b, c, 0, 0, 0);
}

// ---- fused conversions: blocks 0..8191 pack x; 8192..8831 transpose W ----
// x: hidden (B,T,P,D) f32 -> xb (B,P,T,D) bf16
// W: (C=1024,N) f32 -> Wt (N,1024) bf16 via 64x64 LDS transpose tiles
__global__ __launch_bounds__(256) void conv_all(
    const float* __restrict__ hs, const float* __restrict__ Wq,
    const float* __restrict__ Wk, const float* __restrict__ Wv,
    const float* __restrict__ Wo, unsigned short* __restrict__ xb,
    unsigned short* __restrict__ wqkv, unsigned short* __restrict__ wot) {
  __shared__ float tile[64][65];
  int bid = blockIdx.x, tid = threadIdx.x;
  if (bid < 8192) {
    int gid = bid * 256 + tid;
    size_t e = (size_t)gid * 4;
    int r = (int)(e >> 10);          // bp*512 + t
    int d = (int)(e & 1023);
    int b = r >> 12, p = (r >> 9) & 7, t = r & 511;
    const float4* src = (const float4*)(hs + ((((size_t)b * 512 + t) * 8 + p) << 10) + d);
    float4 v = *src;
    us4 o;
    o.x = f2bf(v.x); o.y = f2bf(v.y); o.z = f2bf(v.z); o.w = f2bf(v.w);
    *(us4*)(xb + e) = o;
    return;
  }
  int tb = bid - 8192;
  const float* W; unsigned short* Wt; int N, tc0, tn0;
  if (tb < 256)      { W = Wq; Wt = wqkv;                       N = 1024; tc0 = (tb >> 4) * 64;          tn0 = (tb & 15) * 64; }
  else if (tb < 320) { W = Wk; Wt = wqkv + (size_t)1024 * 1024; N = 256;  tc0 = ((tb - 256) >> 2) * 64;  tn0 = ((tb - 256) & 3) * 64; }
  else if (tb < 384) { W = Wv; Wt = wqkv + (size_t)1280 * 1024; N = 256;  tc0 = ((tb - 320) >> 2) * 64;  tn0 = ((tb - 320) & 3) * 64; }
  else               { W = Wo; Wt = wot;                        N = 1024; tc0 = ((tb - 384) >> 4) * 64;  tn0 = ((tb - 384) & 15) * 64; }
  int tr = tid >> 4, tc = tid & 15;
#pragma unroll
  for (int i = 0; i < 4; ++i) {
    int c = tr + i * 16;
    float4 v = *(const float4*)(W + (size_t)(tc0 + c) * N + tn0 + tc * 4);
    tile[c][tc * 4 + 0] = v.x; tile[c][tc * 4 + 1] = v.y;
    tile[c][tc * 4 + 2] = v.z; tile[c][tc * 4 + 3] = v.w;
  }
  __syncthreads();
#pragma unroll
  for (int i = 0; i < 4; ++i) {
    int n = tr + i * 16;
    us4 o;
    o.x = f2bf(tile[tc * 4 + 0][n]); o.y = f2bf(tile[tc * 4 + 1][n]);
    o.z = f2bf(tile[tc * 4 + 2][n]); o.w = f2bf(tile[tc * 4 + 3][n]);
    *(us4*)(Wt + (size_t)(tn0 + n) * 1024 + tc0 + tc * 4) = o;
  }
}

// ---- 128x128x(K=1024) bf16 GEMM, B^T input, register-pipelined staging ---
// K-loop: global->VGPR prefetch of tile k+1 issued after barrier-2, lands
// during the 32-MFMA compute phase; ds_write_b128 stages it next iteration.
// MODE 0: QKV projection, RoPE fused for Q/K blocks; Q scaled by 0.125.
//         tn 0..7 -> qb (rope'd, *0.125); 8..9 -> kb (rope'd);
//         10..11 -> vtb TRANSPOSED ((bp,kvh,d),t)
// MODE 1: O projection. writes fp32 out[(b,t,p),col].
template <int NT, int MODE>
__global__ __launch_bounds__(256, 3) void gemm_bt(
    const unsigned short* __restrict__ A, const unsigned short* __restrict__ Bt,
    unsigned short* __restrict__ qb, unsigned short* __restrict__ kb,
    unsigned short* __restrict__ vtb, float* __restrict__ out) {
  constexpr int K = 1024;
  __shared__ __align__(16) unsigned short Sm[128 * 128];   // As | Bs, reused as Cs
  unsigned short* As = Sm;
  unsigned short* Bs = Sm + 128 * 64;
  unsigned short* Cs = Sm;

  int tid = threadIdx.x;
  int lane = tid & 63, wid = tid >> 6;
  int quad = lane >> 4, lo = lane & 15;
  int tn = blockIdx.x % NT, tm = blockIdx.x / NT;
  int wm = (wid >> 1) * 64, wn = (wid & 1) * 64;
  int srow = lane >> 3, schunk = lane & 7;

  f32x4 z = {0.f, 0.f, 0.f, 0.f};
  f32x4 acc[4][4];
  for (int i = 0; i < 4; ++i) for (int j = 0; j < 4; ++j) acc[i][j] = z;

  // per-lane fixed staging addresses: row = wid*8 + i*32 + srow, cg = schunk^srow
  int cg = schunk ^ srow;
  const unsigned short* pa = A + ((size_t)(tm * 128) + wid * 8 + srow) * K + cg * 8;
  const unsigned short* pb = Bt + ((size_t)(tn * 128) + wid * 8 + srow) * K + cg * 8;
  unsigned short* wA = As + (size_t)(wid * 8 + srow * 0) * 0;  // (unused, see below)
  // LDS dest (bytes): (wid*8 + i*32)*128 + lane*16
  char* dA = (char*)As + (wid * 8) * 128 + lane * 16;
  char* dB = (char*)Bs + (wid * 8) * 128 + lane * 16;

  us8 ra[4], rb[4];
#pragma unroll
  for (int i = 0; i < 4; ++i) {      // prologue: tile k0=0
    ra[i] = *(const us8*)(pa + (size_t)i * 32 * K);
    rb[i] = *(const us8*)(pb + (size_t)i * 32 * K);
  }

  for (int k0 = 0; k0 < K; k0 += 64) {
    __syncthreads();                 // readers of previous tile done
#pragma unroll
    for (int i = 0; i < 4; ++i) {    // stage regs -> LDS
      *(us8*)(dA + i * 32 * 128) = ra[i];
      *(us8*)(dB + i * 32 * 128) = rb[i];
    }
    __syncthreads();                 // staged tile visible
    if (k0 + 64 < K) {
#pragma unroll
      for (int i = 0; i < 4; ++i) {  // prefetch next tile; lands under MFMA
        ra[i] = *(const us8*)(pa + (size_t)i * 32 * K + k0 + 64);
        rb[i] = *(const us8*)(pb + (size_t)i * 32 * K + k0 + 64);
      }
    }
#pragma unroll
    for (int kk = 0; kk < 64; kk += 32) {
      bf16x8 af[4], bb[4];
#pragma unroll
      for (int mi = 0; mi < 4; ++mi) {
        int row = wm + mi * 16 + lo;
        int cgx = (quad + (kk >> 3)) ^ (row & 7);
        af[mi] = *(const bf16x8*)(As + (size_t)row * 64 + cgx * 8);
      }
#pragma unroll
      for (int ni = 0; ni < 4; ++ni) {
        int row = wn + ni * 16 + lo;
        int cgx = (quad + (kk >> 3)) ^ (row & 7);
        bb[ni] = *(const bf16x8*)(Bs + (size_t)row * 64 + cgx * 8);
      }
#pragma unroll
      for (int mi = 0; mi < 4; ++mi)
#pragma unroll
        for (int ni = 0; ni < 4; ++ni)
          acc[mi][ni] = mfma16(af[mi], bb[ni], acc[mi][ni]);
    }
  }

  __syncthreads();   // all waves done reading As/Bs before Cs reuse

  // epilogue: C/D layout col = lane&15, row = quad*4 + reg  [m89/m91]
  if (MODE == 0 && tn < 10) {
    float qscale = (tn < 8) ? 0.125f : 1.0f;   // fold 1/sqrt(HD) into Q
#pragma unroll
    for (int mi = 0; mi < 4; ++mi)
#pragma unroll
      for (int r = 0; r < 4; ++r) {
        int t = (tm * 128 + wm + mi * 16 + quad * 4 + r) & 511;
#pragma unroll
        for (int ni = 0; ni < 2; ++ni) {
          float inv = exp2f((float)(ni * 16 + lo) * -0.41524101186092029f);
          float ang = (float)t * inv;
          float s, c;
          __sincosf(ang, &s, &c);
          float x1 = acc[mi][ni][r], x2 = acc[mi][ni + 2][r];
          acc[mi][ni][r]     = (x1 * c - x2 * s) * qscale;
          acc[mi][ni + 2][r] = (x1 * s + x2 * c) * qscale;
        }
      }
#pragma unroll
    for (int mi = 0; mi < 4; ++mi)
#pragma unroll
      for (int ni = 0; ni < 4; ++ni)
#pragma unroll
        for (int r = 0; r < 4; ++r) {
          int row = wm + mi * 16 + quad * 4 + r;
          int col = wn + ni * 16 + lo;
          int cs = col ^ (((row >> 2) & 3) << 3);
          Cs[row * 128 + cs] = f2bf(acc[mi][ni][r]);
        }
    __syncthreads();
    int tc = tid & 15, ro = tid >> 4;
#pragma unroll
    for (int it = 0; it < 8; ++it) {
      int row = ro + 16 * it;
      int cs = (tc * 8) ^ (((row >> 2) & 3) << 3);
      us8 v = *(const us8*)(Cs + row * 128 + cs);
      size_t grow = (size_t)(tm * 128 + row);
      if (tn < 8) {
        *(us8*)(qb + grow * 1024 + tn * 128 + tc * 8) = v;
      } else {
        *(us8*)(kb + grow * 256 + (tn - 8) * 128 + tc * 8) = v;
      }
    }
  } else {
    for (int mi = 0; mi < 4; ++mi) {
      for (int ni = 0; ni < 4; ++ni) {
        int col = tn * 128 + wn + ni * 16 + lo;
        for (int r = 0; r < 4; ++r) {
          int grow = tm * 128 + wm + mi * 16 + quad * 4 + r;
          float val = acc[mi][ni][r];
          if (MODE == 0) {
            int cc = col - 1280;
            int hh = cc >> 6, dd = cc & 63;
            int bp = grow >> 9, t = grow & 511;
            vtb[(((size_t)(bp * 4 + hh)) * 64 + dd) * 512 + t] = f2bf(val);
          } else {
            int bp = grow >> 9, t = grow & 511;
            int b = bp >> 3, p = bp & 7;
            out[((((size_t)b * 512 + t) * 8 + p) << 10) + col] = val;
          }
        }
      }
    }
  }
}

// ---- attention: transposed-S 32x32x16 MFMA, fixed-max softmax ------------
__global__ __launch_bounds__(256, 4) void attn(
    const unsigned short* __restrict__ qb, const unsigned short* __restrict__ kb,
    const unsigned short* __restrict__ vtb, unsigned short* __restrict__ ao) {
  __shared__ __align__(16) unsigned short Qs[128 * 64];
  __shared__ __align__(16) unsigned short Ks[64 * 64];
  __shared__ __align__(16) unsigned short Vs[64 * 64];   // V^T: [d][key]

  int tid = threadIdx.x;
  int lane = tid & 63, wid = tid >> 6;
  int lo32 = lane & 31, hl = lane >> 5;
  int qt = blockIdx.x & 3, bph = blockIdx.x >> 2;
  int head = bph & 15, bp = bph >> 4;
  int kvh = head >> 2;
  int t0 = qt * 128;
  int srow = lane >> 3, schunk = lane & 7;

  const unsigned short* qg = qb + ((size_t)(bp * 512 + t0)) * 1024 + head * 64;
  const unsigned short* kg = kb + ((size_t)bp * 512) * 256 + kvh * 64;
  const unsigned short* vg = vtb + ((size_t)(bp * 4 + kvh)) * 64 * 512;

  for (int i = 0; i < 4; ++i) {    // stage Q once: 128 rows x 128B
    int row = wid * 8 + i * 32 + srow;
    int cg = schunk ^ (row & 7);
    ld_lds16(qg + (size_t)row * 1024 + cg * 8, (char*)Qs + (wid * 8 + i * 32) * 128);
  }

  f32x16 z16 = {0.f};
  f32x16 o0 = z16, o1 = z16;
  float psum = 0.f;
  int qrow = wid * 32 + lo32;

  for (int kt = 0; kt < 512; kt += 64) {
    __syncthreads();
    for (int i = 0; i < 2; ++i) {  // stage 64 keys of K and V^T
      int row = wid * 8 + i * 32 + srow;
      int cg = schunk ^ (row & 7);
      ld_lds16(kg + (size_t)(kt + row) * 256 + cg * 8, (char*)Ks + (wid * 8 + i * 32) * 128);
      ld_lds16(vg + (size_t)row * 512 + kt + cg * 8, (char*)Vs + (wid * 8 + i * 32) * 128);
    }
    __syncthreads();

    // S^T = K . Q^T over d=64 (4 chunks of K=16)
    f32x16 st0 = z16, st1 = z16;
#pragma unroll
    for (int kkc = 0; kkc < 4; ++kkc) {
      int ch = 2 * kkc + hl;
      bf16x8 qf = *(const bf16x8*)(Qs + (size_t)qrow * 64 + ((ch ^ (qrow & 7)) * 8));
      bf16x8 kf0 = *(const bf16x8*)(Ks + (size_t)lo32 * 64 + ((ch ^ (lo32 & 7)) * 8));
      bf16x8 kf1 = *(const bf16x8*)(Ks + (size_t)(32 + lo32) * 64 + ((ch ^ (lo32 & 7)) * 8));
      st0 = mfma32(kf0, qf, st0);
      st1 = mfma32(kf1, qf, st1);
    }

    // exp (no max subtraction; scale pre-folded into Q), pack, PV
#pragma unroll
    for (int t = 0; t < 2; ++t) {
      const f32x16& stv = t ? st1 : st0;
      unsigned pk[8], xpk[8];
#pragma unroll
      for (int p = 0; p < 8; ++p) {
        float e0 = __expf(stv[2 * p]);
        float e1 = __expf(stv[2 * p + 1]);
        psum += e0 + e1;
        pk[p] = ((__float_as_uint(e0) + 0x8000u) >> 16) |
                ((__float_as_uint(e1) + 0x8000u) & 0xffff0000u);
      }
#pragma unroll
      for (int p = 0; p < 8; ++p) xpk[p] = (unsigned)__shfl_xor((int)pk[p], 32);
#pragma unroll
      for (int cc = 0; cc < 2; ++cc) {
        int o = cc * 4;
        union { unsigned u[4]; bf16x8 v; } af;
        if (hl == 0) {
          af.u[0] = pk[o];      af.u[1] = pk[o + 1];
          af.u[2] = xpk[o];     af.u[3] = xpk[o + 1];
        } else {
          af.u[0] = xpk[o + 2]; af.u[1] = xpk[o + 3];
          af.u[2] = pk[o + 2];  af.u[3] = pk[o + 3];
        }
        int vch = 2 * (t * 2 + cc) + hl;
        bf16x8 v0 = *(const bf16x8*)(Vs + (size_t)lo32 * 64 + ((vch ^ (lo32 & 7)) * 8));
        bf16x8 v1 = *(const bf16x8*)(Vs + (size_t)(32 + lo32) * 64 + ((vch ^ (lo32 & 7)) * 8));
        o0 = mfma32(af.v, v0, o0);
        o1 = mfma32(af.v, v1, o1);
      }
    }
  }

  // normalize and store: D layout col=lane&31=d, row q_r=(r&3)+8*(r>>2)+4*hl
  psum += __shfl_xor(psum, 32);
  float inv = 1.f / psum;          // lane holds inv for q = lo32
#pragma unroll
  for (int r = 0; r < 16; ++r) {
    int q_r = (r & 3) + 8 * (r >> 2) + 4 * hl;
    float sc = __shfl(inv, q_r);   // holder lane q_r (lo32=q_r)
    size_t grow = (size_t)(bp * 512 + t0 + wid * 32 + q_r);
    ao[grow * 1024 + head * 64 + lo32]      = f2bf(o0[r] * sc);
    ao[grow * 1024 + head * 64 + 32 + lo32] = f2bf(o1[r] * sc);
  }
}

extern "C" void kernel_launch(void* const* d_in, const int* in_sizes, int n_in,
                              void* d_out, int out_size, void* d_ws, size_t ws_size,
                              hipStream_t stream) {
  const float* hs = (const float*)d_in[0];
  const float* Wq = (const float*)d_in[1];
  const float* Wk = (const float*)d_in[2];
  const float* Wv = (const float*)d_in[3];
  const float* Wo = (const float*)d_in[4];
  float* out = (float*)d_out;

  unsigned short* xb   = (unsigned short*)d_ws;                 // 8192*1024
  unsigned short* wqkv = xb + (size_t)8192 * 1024;              // 1536*1024
  unsigned short* wot  = wqkv + (size_t)1536 * 1024;            // 1024*1024
  unsigned short* qbuf = wot + (size_t)1024 * 1024;             // 8192*1024
  unsigned short* kbuf = qbuf + (size_t)8192 * 1024;            // 8192*256
  unsigned short* vtb  = kbuf + (size_t)8192 * 256;             // 8192*256
  unsigned short* ao   = xb;                                    // alias

  conv_all<<<8832, 256, 0, stream>>>(hs, Wq, Wk, Wv, Wo, xb, wqkv, wot);
  gemm_bt<12, 0><<<768, 256, 0, stream>>>(xb, wqkv, qbuf, kbuf, vtb, nullptr);
  attn<<<1024, 256, 0, stream>>>(qbuf, kbuf, vtb, ao);
  gemm_bt<8, 1><<<512, 256, 0, stream>>>(ao, wot, nullptr, nullptr, nullptr, out);
}